// Round 3
// baseline (419.960 us; speedup 1.0000x reference)
//
#include <hip/hip_runtime.h>
#include <cstdint>
#include <cstddef>

#define TOK 4096
#define DM 768
#define HID 2048
#define NE 8

typedef __attribute__((ext_vector_type(8))) short bf16x8;
typedef __attribute__((ext_vector_type(4))) float f32x4;

// async global->LDS: dest = wave-uniform base + lane*16; SOURCE is per-lane.
#define ASYNC16(GP, LP) \
  __builtin_amdgcn_global_load_lds((__attribute__((address_space(1))) void*)(GP), \
                                   (__attribute__((address_space(3))) void*)(LP), 16, 0, 0)

__device__ __forceinline__ unsigned short f2bf(float f) {
  unsigned int u = __float_as_uint(f);
  u += 0x7FFF + ((u >> 16) & 1);   // RNE
  return (unsigned short)(u >> 16);
}
__device__ __forceinline__ unsigned int pack2(float a, float b) {
  return (unsigned)f2bf(a) | ((unsigned)f2bf(b) << 16);
}
__device__ __forceinline__ int padded_off(const int* counts, int e) {
  int o = 0;
  for (int i = 0; i < e; ++i) o += (counts[i] + 127) & ~127;
  return o;
}

// ---------------- K_gate: gating only (NO atomics) ----------------
__global__ __launch_bounds__(256)
void k_gate(const float* __restrict__ x, const float* __restrict__ wgw,
            const float* __restrict__ wgb,
            int* __restrict__ eidx, float* __restrict__ gatep,
            float* __restrict__ cepart)
{
  __shared__ float ce_loc[4][NE];
  const int lane = threadIdx.x & 63;
  const int w = threadIdx.x >> 6;
  const int t = blockIdx.x * 4 + w;
  float acc[NE];
#pragma unroll
  for (int e = 0; e < NE; ++e) acc[e] = 0.f;
  const float* xr = x + (size_t)t * DM;
#pragma unroll
  for (int j = 0; j < DM / 64; ++j) {
    float xv = xr[j * 64 + lane];
#pragma unroll
    for (int e = 0; e < NE; ++e) acc[e] += xv * wgw[e * DM + j * 64 + lane];
  }
#pragma unroll
  for (int e = 0; e < NE; ++e) {
    float v = acc[e];
#pragma unroll
    for (int off = 32; off >= 1; off >>= 1) v += __shfl_xor(v, off);
    acc[e] = v + wgb[e];
  }
  float mx = acc[0]; int ai = 0;
#pragma unroll
  for (int e = 1; e < NE; ++e) if (acc[e] > mx) { mx = acc[e]; ai = e; }
  float p[NE]; float se = 0.f;
#pragma unroll
  for (int e = 0; e < NE; ++e) { p[e] = expf(acc[e] - mx); se += p[e]; }
  float inv = 1.f / se;
  if (lane == 0) {
#pragma unroll
    for (int e = 0; e < NE; ++e) ce_loc[w][e] = p[e] * inv;
    eidx[t] = ai;
    gatep[t] = p[ai] * inv;
  }
  __syncthreads();
  if (threadIdx.x < NE) {
    float s = ce_loc[0][threadIdx.x] + ce_loc[1][threadIdx.x]
            + ce_loc[2][threadIdx.x] + ce_loc[3][threadIdx.x];
    cepart[blockIdx.x * NE + threadIdx.x] = s;
  }
}

// ---------------- K_count: single-block counting sort + aux ----------------
__global__ __launch_bounds__(256)
void k_count(const int* __restrict__ eidx, const float* __restrict__ gatep,
             const float* __restrict__ cepart,
             int* __restrict__ prow_arr, int* __restrict__ tlist,
             float* __restrict__ gate_b, int* __restrict__ counts_g,
             float* __restrict__ aux_out)
{
  __shared__ int hist[256][NE];
  __shared__ float fs[256][NE];
  __shared__ int po_s[NE], cnt_s[NE];
  const int tid = threadIdx.x;
  int own[NE], v[NE], el[16];
#pragma unroll
  for (int e = 0; e < NE; ++e) own[e] = 0;
#pragma unroll
  for (int j = 0; j < 16; ++j) {
    el[j] = eidx[tid * 16 + j];
#pragma unroll
    for (int e = 0; e < NE; ++e) own[e] += (el[j] == e) ? 1 : 0;
  }
#pragma unroll
  for (int e = 0; e < NE; ++e) { v[e] = own[e]; hist[tid][e] = v[e]; }
  __syncthreads();
  for (int st = 1; st < 256; st <<= 1) {
    int add[NE];
#pragma unroll
    for (int e = 0; e < NE; ++e) add[e] = (tid >= st) ? hist[tid - st][e] : 0;
    __syncthreads();
#pragma unroll
    for (int e = 0; e < NE; ++e) { v[e] += add[e]; hist[tid][e] = v[e]; }
    __syncthreads();
  }
  if (tid == 0) {
    int o = 0;
#pragma unroll
    for (int e = 0; e < NE; ++e) {
      int c = hist[255][e];
      cnt_s[e] = c; counts_g[e] = c; po_s[e] = o;
      o += (c + 127) & ~127;
    }
  }
  __syncthreads();
  int run[NE];
#pragma unroll
  for (int e = 0; e < NE; ++e) run[e] = po_s[e] + v[e] - own[e];
#pragma unroll
  for (int j = 0; j < 16; ++j) {
    const int t = tid * 16 + j;
    const int e = el[j];
    int p = 0;
#pragma unroll
    for (int k = 0; k < NE; ++k) if (e == k) p = run[k]++;
    prow_arr[t] = p;
    tlist[p] = t;
    gate_b[p] = gatep[t];
  }
  // aux reduce
  float s[NE];
#pragma unroll
  for (int e = 0; e < NE; ++e) s[e] = 0.f;
  for (int bb = tid; bb < 1024; bb += 256)
#pragma unroll
    for (int e = 0; e < NE; ++e) s[e] += cepart[bb * NE + e];
#pragma unroll
  for (int e = 0; e < NE; ++e) fs[tid][e] = s[e];
  __syncthreads();
  for (int st = 128; st > 0; st >>= 1) {
    if (tid < st)
#pragma unroll
      for (int e = 0; e < NE; ++e) fs[tid][e] += fs[tid + st][e];
    __syncthreads();
  }
  if (tid == 0) {
    float aux = 0.f;
    for (int e = 0; e < NE; ++e)
      aux += ((float)cnt_s[e] / 4096.f) * (fs[0][e] / 4096.f);
    aux_out[0] = 0.05f * 8.f * aux;
  }
}

// ---------------- K2: scatter x rows (row-major bf16) + zero y ----------------
__global__ __launch_bounds__(256)
void k2_scatter_zero(const float* __restrict__ x, const int* __restrict__ prow_arr,
                     unsigned short* __restrict__ xb, float* __restrict__ y)
{
  const int b = blockIdx.x;
  if (b < 1024) {
    const int lane = threadIdx.x & 63;
    const int w = threadIdx.x >> 6;
    const int t = b * 4 + w;
    const int prow = prow_arr[t];
    const float4* src4 = (const float4*)(x + (size_t)t * DM);
    uint2* dst = (uint2*)(xb + (size_t)prow * DM);
#pragma unroll
    for (int c = 0; c < 3; ++c) {
      float4 v = src4[lane + c * 64];
      uint2 d; d.x = pack2(v.x, v.y); d.y = pack2(v.z, v.w);
      dst[lane + c * 64] = d;
    }
  } else {
    float4* y4 = (float4*)y;
    const int base = (b - 1024) * 1536 + threadIdx.x;
#pragma unroll
    for (int c = 0; c < 6; ++c) {
      float4 z; z.x = 0.f; z.y = 0.f; z.z = 0.f; z.w = 0.f;
      y4[base + c * 256] = z;
    }
  }
}

// Dense tile lookup: tile index -> (expert, tm) via prefix scan of
// ceil(counts[e]/128). Max total tiles = 4096/128 + 8 = 40.
__device__ __forceinline__ bool tile_lookup(const int* __restrict__ counts,
                                            int tile, int& e, int& tm) {
  int acc = 0, fe = -1, ftm = 0;
#pragma unroll
  for (int i = 0; i < NE; ++i) {
    int nt = (counts[i] + 127) >> 7;
    if (fe < 0 && tile < acc + nt) { fe = i; ftm = tile - acc; }
    acc += nt;
  }
  if (fe < 0) return false;
  e = fe; tm = ftm;
  return true;
}

// ---------------- FFN1: h = silu(x@Wu)*(x@Wv)*gate ----------------
// Fused fp32->bf16. 128M x 128N, BK=32, double-buffered, 256 thr = 4 waves
// (2x2, wave tile 64x64). LDS/buffer: A 8K | Bu 8K | Bv 8K -> 48KB total ->
// 3 blocks/CU (MLP: drain stalls of one block overlap other blocks' work).
__global__ __launch_bounds__(256, 3)
void k_ffn1(const float* __restrict__ Wu, const float* __restrict__ Wv,
            const unsigned short* __restrict__ xb, const float* __restrict__ gate_b,
            const int* __restrict__ counts, unsigned short* __restrict__ h)
{
  const int bid = blockIdx.x;
  const int tn = bid & 15;
  const int tile = bid >> 4;
  int e, tm;
  if (!tile_lookup(counts, tile, e, tm)) return;
  const int Me = counts[e];
  const int prowbase = padded_off(counts, e) + tm * 128;

  __shared__ __align__(16) char Sh[49152];   // [2][A 8K | Bu 8K | Bv 8K]

  const int tid = threadIdx.x;
  const int lane = tid & 63;
  const int w = tid >> 6;                    // 0..3
  const int wm = w >> 1, wn = w & 1;

  // ---- A async staging: 8 chunks of 1KB (128 rows x 32k bf16); wave w: 2w,2w+1
  const int c0 = w * 2, c1 = c0 + 1;
  const int mA0 = c0 * 16 + (lane >> 2), sA0 = lane & 3;
  const int ko0 = (sA0 - mA0 - (mA0 >> 2)) & 3;
  const char* aSrc0 = (const char*)xb + (size_t)(prowbase + mA0) * (DM * 2) + ko0 * 16;
  const int mA1 = c1 * 16 + (lane >> 2), sA1 = lane & 3;
  const int ko1 = (sA1 - mA1 - (mA1 >> 2)) & 3;
  const char* aSrc1 = (const char*)xb + (size_t)(prowbase + mA1) * (DM * 2) + ko1 * 16;

  // ---- B reg-staging: thread (w,lane) -> k-octet w, columns n0=2*lane, n0+1
  // (float2 loads: 512B coalesced runs/wave/row)
  const int koW = w;
  const int n0 = lane * 2, n1 = n0 + 1;
  const unsigned offB0 = (unsigned)(n0 * 4 + ((koW + n0 + (n0 >> 2)) & 3)) * 16;
  const unsigned offB1 = (unsigned)(n1 * 4 + ((koW + n1 + (n1 >> 2)) & 3)) * 16;
  const float* srcU = Wu + (size_t)e * DM * HID + (size_t)(koW * 8) * HID + tn * 128 + n0;
  const float* srcV = Wv + (size_t)e * DM * HID + (size_t)(koW * 8) * HID + tn * 128 + n0;

  // ---- compute-side LDS read offsets
  const int lc = lane & 15, q = lane >> 4;
  unsigned offA[4], offU[4], offV[4];
#pragma unroll
  for (int i = 0; i < 4; ++i) {
    int m = wm * 64 + i * 16 + lc;
    offA[i] = (unsigned)(m * 4 + ((q + m + (m >> 2)) & 3)) * 16;
    int n = wn * 64 + i * 16 + lc;
    unsigned ob = (unsigned)(n * 4 + ((q + n + (n >> 2)) & 3)) * 16;
    offU[i] = 8192u + ob;
    offV[i] = 16384u + ob;
  }

  f32x4 accU[4][4], accV[4][4];
#pragma unroll
  for (int i = 0; i < 4; ++i)
#pragma unroll
    for (int j = 0; j < 4; ++j)
#pragma unroll
      for (int k = 0; k < 4; ++k) { accU[i][j][k] = 0.f; accV[i][j][k] = 0.f; }

  float2 fu[8], fv[8];
  // ---- prologue: stage step 0 into buffer 0
  ASYNC16(aSrc0, Sh + c0 * 1024); aSrc0 += 64;
  ASYNC16(aSrc1, Sh + c1 * 1024); aSrc1 += 64;
#pragma unroll
  for (int j = 0; j < 8; ++j) {
    fu[j] = *(const float2*)(srcU + (size_t)j * HID);
    fv[j] = *(const float2*)(srcV + (size_t)j * HID);
  }
  srcU += (size_t)32 * HID; srcV += (size_t)32 * HID;
  {
    uint4 u0, u1, v0, v1;
    u0.x = pack2(fu[0].x, fu[1].x); u0.y = pack2(fu[2].x, fu[3].x);
    u0.z = pack2(fu[4].x, fu[5].x); u0.w = pack2(fu[6].x, fu[7].x);
    u1.x = pack2(fu[0].y, fu[1].y); u1.y = pack2(fu[2].y, fu[3].y);
    u1.z = pack2(fu[4].y, fu[5].y); u1.w = pack2(fu[6].y, fu[7].y);
    v0.x = pack2(fv[0].x, fv[1].x); v0.y = pack2(fv[2].x, fv[3].x);
    v0.z = pack2(fv[4].x, fv[5].x); v0.w = pack2(fv[6].x, fv[7].x);
    v1.x = pack2(fv[0].y, fv[1].y); v1.y = pack2(fv[2].y, fv[3].y);
    v1.z = pack2(fv[4].y, fv[5].y); v1.w = pack2(fv[6].y, fv[7].y);
    *(uint4*)(Sh + 8192 + offB0) = u0;
    *(uint4*)(Sh + 8192 + offB1) = u1;
    *(uint4*)(Sh + 16384 + offB0) = v0;
    *(uint4*)(Sh + 16384 + offB1) = v1;
  }
  __syncthreads();

  for (int kt = 0; kt < 24; ++kt) {
    char* bufc = Sh + (unsigned)(kt & 1) * 24576u;
    char* bufn = Sh + (unsigned)((kt + 1) & 1) * 24576u;
    const bool more = (kt + 1) < 24;
    if (more) {                       // issue next step's loads BEFORE compute
      ASYNC16(aSrc0, bufn + c0 * 1024); aSrc0 += 64;
      ASYNC16(aSrc1, bufn + c1 * 1024); aSrc1 += 64;
#pragma unroll
      for (int j = 0; j < 8; ++j) {
        fu[j] = *(const float2*)(srcU + (size_t)j * HID);
        fv[j] = *(const float2*)(srcV + (size_t)j * HID);
      }
      srcU += (size_t)32 * HID; srcV += (size_t)32 * HID;
    }
    bf16x8 a[4], bu[4], bv[4];
#pragma unroll
    for (int i = 0; i < 4; ++i) a[i] = *(const bf16x8*)(bufc + offA[i]);
#pragma unroll
    for (int j = 0; j < 4; ++j) {
      bu[j] = *(const bf16x8*)(bufc + offU[j]);
      bv[j] = *(const bf16x8*)(bufc + offV[j]);
    }
#pragma unroll
    for (int i = 0; i < 4; ++i)
#pragma unroll
      for (int j = 0; j < 4; ++j) {
        accU[i][j] = __builtin_amdgcn_mfma_f32_16x16x32_bf16(a[i], bu[j], accU[i][j], 0, 0, 0);
        accV[i][j] = __builtin_amdgcn_mfma_f32_16x16x32_bf16(a[i], bv[j], accV[i][j], 0, 0, 0);
      }
    if (more) {                       // convert + write next buffer
      uint4 u0, u1, v0, v1;
      u0.x = pack2(fu[0].x, fu[1].x); u0.y = pack2(fu[2].x, fu[3].x);
      u0.z = pack2(fu[4].x, fu[5].x); u0.w = pack2(fu[6].x, fu[7].x);
      u1.x = pack2(fu[0].y, fu[1].y); u1.y = pack2(fu[2].y, fu[3].y);
      u1.z = pack2(fu[4].y, fu[5].y); u1.w = pack2(fu[6].y, fu[7].y);
      v0.x = pack2(fv[0].x, fv[1].x); v0.y = pack2(fv[2].x, fv[3].x);
      v0.z = pack2(fv[4].x, fv[5].x); v0.w = pack2(fv[6].x, fv[7].x);
      v1.x = pack2(fv[0].y, fv[1].y); v1.y = pack2(fv[2].y, fv[3].y);
      v1.z = pack2(fv[4].y, fv[5].y); v1.w = pack2(fv[6].y, fv[7].y);
      *(uint4*)(bufn + 8192 + offB0) = u0;
      *(uint4*)(bufn + 8192 + offB1) = u1;
      *(uint4*)(bufn + 16384 + offB0) = v0;
      *(uint4*)(bufn + 16384 + offB1) = v1;
    }
    __syncthreads();
  }

  const int colbase = tn * 128 + wn * 64;
  const int rlane = (lane >> 4) * 4;
  const int clane = lane & 15;
#pragma unroll
  for (int i = 0; i < 4; ++i) {
#pragma unroll
    for (int rr = 0; rr < 4; ++rr) {
      int rowIn = wm * 64 + i * 16 + rlane + rr;
      if (tm * 128 + rowIn < Me) {
        int prow = prowbase + rowIn;
        float g = gate_b[prow];
        unsigned short* hp = h + (size_t)prow * HID + colbase + clane;
#pragma unroll
        for (int j = 0; j < 4; ++j) {
          float u_ = accU[i][j][rr];
          float v_ = accV[i][j][rr];
          float sv = u_ / (1.f + expf(-u_));
          hp[j * 16] = f2bf(sv * v_ * g);
        }
      }
    }
  }
}

// ---------------- FFN2: y += h @ Wd (split-K=4, atomic f32) ----------------
// Fused fp32->bf16. 128M x 128N, BK=32, double-buffered, 256 thr = 4 waves.
// LDS/buffer: A 8K | B 8K -> 32KB total -> 4-5 blocks/CU.
__global__ __launch_bounds__(256, 4)
void k_ffn2(const float* __restrict__ Wd, const unsigned short* __restrict__ h,
            const int* __restrict__ counts, const int* __restrict__ tlist,
            float* __restrict__ y)
{
  const int bid = blockIdx.x;
  const int inner = bid % 24;
  const int tn = inner % 6;
  const int sk = inner / 6;              // split-K 0..3 (512 k each)
  const int tile = bid / 24;
  int e, tm;
  if (!tile_lookup(counts, tile, e, tm)) return;
  const int Me = counts[e];
  const int prowbase = padded_off(counts, e) + tm * 128;

  __shared__ __align__(16) char Sh[32768];   // [2][A 8K | B 8K]

  const int tid = threadIdx.x;
  const int lane = tid & 63;
  const int w = tid >> 6;
  const int wm = w >> 1, wn = w & 1;

  // ---- A async staging (h rows, bf16), split-K window
  const int c0 = w * 2, c1 = c0 + 1;
  const int mA0 = c0 * 16 + (lane >> 2), sA0 = lane & 3;
  const int ko0 = (sA0 - mA0 - (mA0 >> 2)) & 3;
  const char* aSrc0 = (const char*)h + (size_t)(prowbase + mA0) * (HID * 2) + sk * 1024 + ko0 * 16;
  const int mA1 = c1 * 16 + (lane >> 2), sA1 = lane & 3;
  const int ko1 = (sA1 - mA1 - (mA1 >> 2)) & 3;
  const char* aSrc1 = (const char*)h + (size_t)(prowbase + mA1) * (HID * 2) + sk * 1024 + ko1 * 16;

  // ---- B reg-staging: k-octet w, columns n0=2*lane, n0+1 (float2 loads)
  const int koW = w;
  const int n0 = lane * 2, n1 = n0 + 1;
  const unsigned offB0 = (unsigned)(n0 * 4 + ((koW + n0 + (n0 >> 2)) & 3)) * 16;
  const unsigned offB1 = (unsigned)(n1 * 4 + ((koW + n1 + (n1 >> 2)) & 3)) * 16;
  const float* srcD = Wd + (size_t)e * HID * DM + (size_t)(sk * 512 + koW * 8) * DM + tn * 128 + n0;

  const int lc = lane & 15, q = lane >> 4;
  unsigned offA[4], offBr[4];
#pragma unroll
  for (int i = 0; i < 4; ++i) {
    int m = wm * 64 + i * 16 + lc;
    offA[i] = (unsigned)(m * 4 + ((q + m + (m >> 2)) & 3)) * 16;
    int n = wn * 64 + i * 16 + lc;
    offBr[i] = 8192u + (unsigned)(n * 4 + ((q + n + (n >> 2)) & 3)) * 16;
  }

  f32x4 acc[4][4];
#pragma unroll
  for (int i = 0; i < 4; ++i)
#pragma unroll
    for (int j = 0; j < 4; ++j)
#pragma unroll
      for (int k = 0; k < 4; ++k) acc[i][j][k] = 0.f;

  float2 fd[8];
  // ---- prologue
  ASYNC16(aSrc0, Sh + c0 * 1024); aSrc0 += 64;
  ASYNC16(aSrc1, Sh + c1 * 1024); aSrc1 += 64;
#pragma unroll
  for (int j = 0; j < 8; ++j) fd[j] = *(const float2*)(srcD + (size_t)j * DM);
  srcD += (size_t)32 * DM;
  {
    uint4 d0, d1;
    d0.x = pack2(fd[0].x, fd[1].x); d0.y = pack2(fd[2].x, fd[3].x);
    d0.z = pack2(fd[4].x, fd[5].x); d0.w = pack2(fd[6].x, fd[7].x);
    d1.x = pack2(fd[0].y, fd[1].y); d1.y = pack2(fd[2].y, fd[3].y);
    d1.z = pack2(fd[4].y, fd[5].y); d1.w = pack2(fd[6].y, fd[7].y);
    *(uint4*)(Sh + 8192 + offB0) = d0;
    *(uint4*)(Sh + 8192 + offB1) = d1;
  }
  __syncthreads();

  for (int kt = 0; kt < 16; ++kt) {
    char* bufc = Sh + (unsigned)(kt & 1) * 16384u;
    char* bufn = Sh + (unsigned)((kt + 1) & 1) * 16384u;
    const bool more = (kt + 1) < 16;
    if (more) {
      ASYNC16(aSrc0, bufn + c0 * 1024); aSrc0 += 64;
      ASYNC16(aSrc1, bufn + c1 * 1024); aSrc1 += 64;
#pragma unroll
      for (int j = 0; j < 8; ++j) fd[j] = *(const float2*)(srcD + (size_t)j * DM);
      srcD += (size_t)32 * DM;
    }
    bf16x8 a[4], b[4];
#pragma unroll
    for (int i = 0; i < 4; ++i) a[i] = *(const bf16x8*)(bufc + offA[i]);
#pragma unroll
    for (int j = 0; j < 4; ++j) b[j] = *(const bf16x8*)(bufc + offBr[j]);
#pragma unroll
    for (int i = 0; i < 4; ++i)
#pragma unroll
      for (int j = 0; j < 4; ++j)
        acc[i][j] = __builtin_amdgcn_mfma_f32_16x16x32_bf16(a[i], b[j], acc[i][j], 0, 0, 0);
    if (more) {
      uint4 d0, d1;
      d0.x = pack2(fd[0].x, fd[1].x); d0.y = pack2(fd[2].x, fd[3].x);
      d0.z = pack2(fd[4].x, fd[5].x); d0.w = pack2(fd[6].x, fd[7].x);
      d1.x = pack2(fd[0].y, fd[1].y); d1.y = pack2(fd[2].y, fd[3].y);
      d1.z = pack2(fd[4].y, fd[5].y); d1.w = pack2(fd[6].y, fd[7].y);
      *(uint4*)(bufn + 8192 + offB0) = d0;
      *(uint4*)(bufn + 8192 + offB1) = d1;
    }
    __syncthreads();
  }

  const int colbase = tn * 128 + wn * 64;
  const int rlane = (lane >> 4) * 4;
  const int clane = lane & 15;
#pragma unroll
  for (int i = 0; i < 4; ++i) {
#pragma unroll
    for (int rr = 0; rr < 4; ++rr) {
      int rowIn = wm * 64 + i * 16 + rlane + rr;
      if (tm * 128 + rowIn < Me) {
        int tok = tlist[prowbase + rowIn];
        float* yp = y + (size_t)tok * DM + colbase + clane;
#pragma unroll
        for (int j = 0; j < 4; ++j) atomicAdd(&yp[j * 16], acc[i][j][rr]);
      }
    }
  }
}

extern "C" void kernel_launch(void* const* d_in, const int* in_sizes, int n_in,
                              void* d_out, int out_size, void* d_ws, size_t ws_size,
                              hipStream_t stream)
{
  const float* x   = (const float*)d_in[0];
  const float* wgw = (const float*)d_in[1];
  const float* wgb = (const float*)d_in[2];
  const float* Wu  = (const float*)d_in[3];
  const float* Wv  = (const float*)d_in[4];
  const float* Wd  = (const float*)d_in[5];
  float* out = (float*)d_out;

  char* ws = (char*)d_ws;
  int*   counts = (int*)(ws + 0);                         // 8 ints
  int*   eidx   = (int*)(ws + 256);                       // 4096
  float* gatep  = (float*)(ws + 16640);                   // 4096
  int*   prow   = (int*)(ws + 33024);                     // 4096
  float* cepart = (float*)(ws + 49408);                   // 1024*8
  int*   tlist  = (int*)(ws + 82176);                     // 5120 (padded rows)
  float* gate_b = (float*)(ws + 102656);                  // 5120
  unsigned short* xb  = (unsigned short*)(ws + 123136);   // 5120*768 bf16
  unsigned short* h   = (unsigned short*)(ws + 7987456);  // 5120*2048 bf16

  k_gate<<<1024, 256, 0, stream>>>(x, wgw, wgb, eidx, gatep, cepart);
  k_count<<<1, 256, 0, stream>>>(eidx, gatep, cepart, prow, tlist, gate_b,
                                 counts, out + (size_t)TOK * DM);
  k2_scatter_zero<<<1536, 256, 0, stream>>>(x, prow, xb, out);
  k_ffn1<<<40 * 16, 256, 0, stream>>>(Wu, Wv, xb, gate_b, counts, h);
  k_ffn2<<<40 * 24, 256, 0, stream>>>(Wd, h, counts, tlist, out);
}

// Round 4
// 364.514 us; speedup vs baseline: 1.1521x; 1.1521x over previous
//
#include <hip/hip_runtime.h>
#include <cstdint>
#include <cstddef>

#define TOK 4096
#define DM 768
#define HID 2048
#define NE 8

typedef __attribute__((ext_vector_type(8))) short bf16x8;
typedef __attribute__((ext_vector_type(4))) float f32x4;

// async global->LDS: dest = wave-uniform base + lane*16; SOURCE is per-lane.
#define ASYNC16(GP, LP) \
  __builtin_amdgcn_global_load_lds((__attribute__((address_space(1))) void*)(GP), \
                                   (__attribute__((address_space(3))) void*)(LP), 16, 0, 0)

__device__ __forceinline__ unsigned short f2bf(float f) {
  unsigned int u = __float_as_uint(f);
  u += 0x7FFF + ((u >> 16) & 1);   // RNE
  return (unsigned short)(u >> 16);
}
__device__ __forceinline__ unsigned int pack2(float a, float b) {
  return (unsigned)f2bf(a) | ((unsigned)f2bf(b) << 16);
}
__device__ __forceinline__ int padded_off(const int* counts, int e) {
  int o = 0;
  for (int i = 0; i < e; ++i) o += (counts[i] + 127) & ~127;
  return o;
}

// ---------------- K_gate: gating only (NO atomics) ----------------
__global__ __launch_bounds__(256)
void k_gate(const float* __restrict__ x, const float* __restrict__ wgw,
            const float* __restrict__ wgb,
            int* __restrict__ eidx, float* __restrict__ gatep,
            float* __restrict__ cepart)
{
  __shared__ float ce_loc[4][NE];
  const int lane = threadIdx.x & 63;
  const int w = threadIdx.x >> 6;
  const int t = blockIdx.x * 4 + w;
  float acc[NE];
#pragma unroll
  for (int e = 0; e < NE; ++e) acc[e] = 0.f;
  const float* xr = x + (size_t)t * DM;
#pragma unroll
  for (int j = 0; j < DM / 64; ++j) {
    float xv = xr[j * 64 + lane];
#pragma unroll
    for (int e = 0; e < NE; ++e) acc[e] += xv * wgw[e * DM + j * 64 + lane];
  }
#pragma unroll
  for (int e = 0; e < NE; ++e) {
    float v = acc[e];
#pragma unroll
    for (int off = 32; off >= 1; off >>= 1) v += __shfl_xor(v, off);
    acc[e] = v + wgb[e];
  }
  float mx = acc[0]; int ai = 0;
#pragma unroll
  for (int e = 1; e < NE; ++e) if (acc[e] > mx) { mx = acc[e]; ai = e; }
  float p[NE]; float se = 0.f;
#pragma unroll
  for (int e = 0; e < NE; ++e) { p[e] = expf(acc[e] - mx); se += p[e]; }
  float inv = 1.f / se;
  if (lane == 0) {
#pragma unroll
    for (int e = 0; e < NE; ++e) ce_loc[w][e] = p[e] * inv;
    eidx[t] = ai;
    gatep[t] = p[ai] * inv;
  }
  __syncthreads();
  if (threadIdx.x < NE) {
    float s = ce_loc[0][threadIdx.x] + ce_loc[1][threadIdx.x]
            + ce_loc[2][threadIdx.x] + ce_loc[3][threadIdx.x];
    cepart[blockIdx.x * NE + threadIdx.x] = s;
  }
}

// ---------------- K_count: single-block counting sort + aux ----------------
__global__ __launch_bounds__(256)
void k_count(const int* __restrict__ eidx, const float* __restrict__ gatep,
             const float* __restrict__ cepart,
             int* __restrict__ prow_arr, int* __restrict__ tlist,
             float* __restrict__ gate_b, int* __restrict__ counts_g,
             float* __restrict__ aux_out)
{
  __shared__ int hist[256][NE];
  __shared__ float fs[256][NE];
  __shared__ int po_s[NE], cnt_s[NE];
  const int tid = threadIdx.x;
  int own[NE], v[NE], el[16];
#pragma unroll
  for (int e = 0; e < NE; ++e) own[e] = 0;
#pragma unroll
  for (int j = 0; j < 16; ++j) {
    el[j] = eidx[tid * 16 + j];
#pragma unroll
    for (int e = 0; e < NE; ++e) own[e] += (el[j] == e) ? 1 : 0;
  }
#pragma unroll
  for (int e = 0; e < NE; ++e) { v[e] = own[e]; hist[tid][e] = v[e]; }
  __syncthreads();
  for (int st = 1; st < 256; st <<= 1) {
    int add[NE];
#pragma unroll
    for (int e = 0; e < NE; ++e) add[e] = (tid >= st) ? hist[tid - st][e] : 0;
    __syncthreads();
#pragma unroll
    for (int e = 0; e < NE; ++e) { v[e] += add[e]; hist[tid][e] = v[e]; }
    __syncthreads();
  }
  if (tid == 0) {
    int o = 0;
#pragma unroll
    for (int e = 0; e < NE; ++e) {
      int c = hist[255][e];
      cnt_s[e] = c; counts_g[e] = c; po_s[e] = o;
      o += (c + 127) & ~127;
    }
  }
  __syncthreads();
  int run[NE];
#pragma unroll
  for (int e = 0; e < NE; ++e) run[e] = po_s[e] + v[e] - own[e];
#pragma unroll
  for (int j = 0; j < 16; ++j) {
    const int t = tid * 16 + j;
    const int e = el[j];
    int p = 0;
#pragma unroll
    for (int k = 0; k < NE; ++k) if (e == k) p = run[k]++;
    prow_arr[t] = p;
    tlist[p] = t;
    gate_b[p] = gatep[t];
  }
  // aux reduce
  float s[NE];
#pragma unroll
  for (int e = 0; e < NE; ++e) s[e] = 0.f;
  for (int bb = tid; bb < 1024; bb += 256)
#pragma unroll
    for (int e = 0; e < NE; ++e) s[e] += cepart[bb * NE + e];
#pragma unroll
  for (int e = 0; e < NE; ++e) fs[tid][e] = s[e];
  __syncthreads();
  for (int st = 128; st > 0; st >>= 1) {
    if (tid < st)
#pragma unroll
      for (int e = 0; e < NE; ++e) fs[tid][e] += fs[tid + st][e];
    __syncthreads();
  }
  if (tid == 0) {
    float aux = 0.f;
    for (int e = 0; e < NE; ++e)
      aux += ((float)cnt_s[e] / 4096.f) * (fs[0][e] / 4096.f);
    aux_out[0] = 0.05f * 8.f * aux;
  }
}

// ---------------- K2: scatter x rows (row-major bf16) + zero y ----------------
__global__ __launch_bounds__(256)
void k2_scatter_zero(const float* __restrict__ x, const int* __restrict__ prow_arr,
                     unsigned short* __restrict__ xb, float* __restrict__ y)
{
  const int b = blockIdx.x;
  if (b < 1024) {
    const int lane = threadIdx.x & 63;
    const int w = threadIdx.x >> 6;
    const int t = b * 4 + w;
    const int prow = prow_arr[t];
    const float4* src4 = (const float4*)(x + (size_t)t * DM);
    uint2* dst = (uint2*)(xb + (size_t)prow * DM);
#pragma unroll
    for (int c = 0; c < 3; ++c) {
      float4 v = src4[lane + c * 64];
      uint2 d; d.x = pack2(v.x, v.y); d.y = pack2(v.z, v.w);
      dst[lane + c * 64] = d;
    }
  } else {
    float4* y4 = (float4*)y;
    const int base = (b - 1024) * 1536 + threadIdx.x;
#pragma unroll
    for (int c = 0; c < 6; ++c) {
      float4 z; z.x = 0.f; z.y = 0.f; z.z = 0.f; z.w = 0.f;
      y4[base + c * 256] = z;
    }
  }
}

// Dense tile lookup: tile index -> (expert, tm) via prefix scan of
// ceil(counts[e]/256). Max total tiles = 4096/256 + 8 = 24 (< 32 cap).
__device__ __forceinline__ bool tile_lookup(const int* __restrict__ counts,
                                            int tile, int& e, int& tm) {
  int acc = 0, fe = -1, ftm = 0;
#pragma unroll
  for (int i = 0; i < NE; ++i) {
    int nt = (counts[i] + 255) >> 8;
    if (fe < 0 && tile < acc + nt) { fe = i; ftm = tile - acc; }
    acc += nt;
  }
  if (fe < 0) return false;
  e = fe; tm = ftm;
  return true;
}

// ---------------- FFN1: h = silu(x@Wu)*(x@Wv)*gate ----------------
// Fused fp32->bf16 conversion. 256M x 128N, BK=32, double-buffered.
// 512 threads = 8 waves (4m x 2n), wave tile 64x64.
// LDS per buffer: A 16KB | Bu 8KB | Bv 8KB  (2 buffers = 64KB).
// XCD-pair swizzle: tile-pair (2p,2p+1) -> XCD p&7, so the tm-pair that
// re-reads the same B panel and the 16 tn-blocks that re-read the same A
// panel all hit the SAME 4-MB L2 instead of bouncing through the LLC.
__global__ __launch_bounds__(512, 2)
void k_ffn1(const float* __restrict__ Wu, const float* __restrict__ Wv,
            const unsigned short* __restrict__ xb, const float* __restrict__ gate_b,
            const int* __restrict__ counts, unsigned short* __restrict__ h)
{
  const int bid = blockIdx.x;                // grid = 32 tiles * 16 tn = 512
  const int xcd = bid & 7;
  const int s = bid >> 3;                    // 0..63
  const int pidx = s >> 5;                   // 0..1
  const int sub = s & 31;                    // 0..31
  const int tile = (xcd + 8 * pidx) * 2 + (sub >> 4);
  const int tn = sub & 15;
  int e, tm;
  if (!tile_lookup(counts, tile, e, tm)) return;
  const int Me = counts[e];
  const int prowbase = padded_off(counts, e) + tm * 256;

  __shared__ __align__(16) char Sh[65536];   // [2][A 16K | Bu 8K | Bv 8K]

  const int tid = threadIdx.x;
  const int lane = tid & 63;
  const int w = tid >> 6;
  const int wm = w >> 1, wn = w & 1;

  // ---- A async staging: 2 chunks of 1KB per wave (16 chunks = 256 rows x 32k)
  const int c0 = w * 2, c1 = w * 2 + 1;
  const int mA0 = c0 * 16 + (lane >> 2), sA0 = lane & 3;
  const int ko0 = (sA0 - mA0 - (mA0 >> 2)) & 3;
  const char* aSrc0 = (const char*)xb + (size_t)(prowbase + mA0) * (DM * 2) + ko0 * 16;
  const int mA1 = c1 * 16 + (lane >> 2), sA1 = lane & 3;
  const int ko1 = (sA1 - mA1 - (mA1 >> 2)) & 3;
  const char* aSrc1 = (const char*)xb + (size_t)(prowbase + mA1) * (DM * 2) + ko1 * 16;

  // ---- B reg-staging: thread -> (nloc, koW); 8 coalesced fp32 loads (256B/wave)
  const int koW = w & 3;
  const int nloc = (w >> 2) * 64 + lane;
  const unsigned offBw = (unsigned)(nloc * 4 + ((koW + nloc + (nloc >> 2)) & 3)) * 16;
  const int ncol = tn * 128 + nloc;
  const float* srcU = Wu + (size_t)e * DM * HID + (size_t)(koW * 8) * HID + ncol;
  const float* srcV = Wv + (size_t)e * DM * HID + (size_t)(koW * 8) * HID + ncol;

  // ---- compute-side LDS read offsets
  const int lc = lane & 15, q = lane >> 4;
  unsigned offA[4], offU[4], offV[4];
#pragma unroll
  for (int i = 0; i < 4; ++i) {
    int m = wm * 64 + i * 16 + lc;
    offA[i] = (unsigned)(m * 4 + ((q + m + (m >> 2)) & 3)) * 16;
    int n = wn * 64 + i * 16 + lc;
    unsigned ob = (unsigned)(n * 4 + ((q + n + (n >> 2)) & 3)) * 16;
    offU[i] = 16384u + ob;
    offV[i] = 24576u + ob;
  }

  f32x4 accU[4][4], accV[4][4];
#pragma unroll
  for (int i = 0; i < 4; ++i)
#pragma unroll
    for (int j = 0; j < 4; ++j)
#pragma unroll
      for (int k = 0; k < 4; ++k) { accU[i][j][k] = 0.f; accV[i][j][k] = 0.f; }

  float fu[8], fv[8];
  // ---- prologue: stage step 0 into buffer 0
  ASYNC16(aSrc0, Sh + c0 * 1024); aSrc0 += 64;
  ASYNC16(aSrc1, Sh + c1 * 1024); aSrc1 += 64;
#pragma unroll
  for (int j = 0; j < 8; ++j) { fu[j] = srcU[(size_t)j * HID]; fv[j] = srcV[(size_t)j * HID]; }
  srcU += (size_t)32 * HID; srcV += (size_t)32 * HID;
  {
    uint4 up, vp;
    up.x = pack2(fu[0], fu[1]); up.y = pack2(fu[2], fu[3]);
    up.z = pack2(fu[4], fu[5]); up.w = pack2(fu[6], fu[7]);
    vp.x = pack2(fv[0], fv[1]); vp.y = pack2(fv[2], fv[3]);
    vp.z = pack2(fv[4], fv[5]); vp.w = pack2(fv[6], fv[7]);
    *(uint4*)(Sh + 16384 + offBw) = up;
    *(uint4*)(Sh + 24576 + offBw) = vp;
  }
  __syncthreads();

  for (int kt = 0; kt < 24; ++kt) {
    char* bufc = Sh + (unsigned)(kt & 1) * 32768u;
    char* bufn = Sh + (unsigned)((kt + 1) & 1) * 32768u;
    const bool more = (kt + 1) < 24;
    if (more) {                       // issue next step's loads BEFORE compute
      ASYNC16(aSrc0, bufn + c0 * 1024); aSrc0 += 64;
      ASYNC16(aSrc1, bufn + c1 * 1024); aSrc1 += 64;
#pragma unroll
      for (int j = 0; j < 8; ++j) { fu[j] = srcU[(size_t)j * HID]; fv[j] = srcV[(size_t)j * HID]; }
      srcU += (size_t)32 * HID; srcV += (size_t)32 * HID;
    }
    bf16x8 a[4], bu[4], bv[4];
#pragma unroll
    for (int i = 0; i < 4; ++i) a[i] = *(const bf16x8*)(bufc + offA[i]);
#pragma unroll
    for (int j = 0; j < 4; ++j) {
      bu[j] = *(const bf16x8*)(bufc + offU[j]);
      bv[j] = *(const bf16x8*)(bufc + offV[j]);
    }
#pragma unroll
    for (int i = 0; i < 4; ++i)
#pragma unroll
      for (int j = 0; j < 4; ++j) {
        accU[i][j] = __builtin_amdgcn_mfma_f32_16x16x32_bf16(a[i], bu[j], accU[i][j], 0, 0, 0);
        accV[i][j] = __builtin_amdgcn_mfma_f32_16x16x32_bf16(a[i], bv[j], accV[i][j], 0, 0, 0);
      }
    if (more) {                       // convert + write next buffer (latency hidden by MFMA)
      uint4 up, vp;
      up.x = pack2(fu[0], fu[1]); up.y = pack2(fu[2], fu[3]);
      up.z = pack2(fu[4], fu[5]); up.w = pack2(fu[6], fu[7]);
      vp.x = pack2(fv[0], fv[1]); vp.y = pack2(fv[2], fv[3]);
      vp.z = pack2(fv[4], fv[5]); vp.w = pack2(fv[6], fv[7]);
      *(uint4*)(bufn + 16384 + offBw) = up;
      *(uint4*)(bufn + 24576 + offBw) = vp;
    }
    __syncthreads();
  }

  const int colbase = tn * 128 + wn * 64;
  const int rlane = (lane >> 4) * 4;
  const int clane = lane & 15;
#pragma unroll
  for (int i = 0; i < 4; ++i) {
#pragma unroll
    for (int rr = 0; rr < 4; ++rr) {
      int rowIn = wm * 64 + i * 16 + rlane + rr;
      if (tm * 256 + rowIn < Me) {
        int prow = prowbase + rowIn;
        float g = gate_b[prow];
        unsigned short* hp = h + (size_t)prow * HID + colbase + clane;
#pragma unroll
        for (int j = 0; j < 4; ++j) {
          float u_ = accU[i][j][rr];
          float v_ = accV[i][j][rr];
          float sv = u_ / (1.f + expf(-u_));
          hp[j * 16] = f2bf(sv * v_ * g);
        }
      }
    }
  }
}

// ---------------- FFN2: y += h @ Wd (split-K=4, atomic f32) ----------------
// Fused fp32->bf16 conversion. 256M x 128N, BK=32, double-buffered.
// LDS per buffer: A 16KB | B 8KB  (2 buffers = 48KB).
// Same XCD-pair swizzle as ffn1.
__global__ __launch_bounds__(512, 2)
void k_ffn2(const float* __restrict__ Wd, const unsigned short* __restrict__ h,
            const int* __restrict__ counts, const int* __restrict__ tlist,
            float* __restrict__ y)
{
  const int bid = blockIdx.x;                // grid = 32 tiles * 24 inner = 768
  const int xcd = bid & 7;
  const int s = bid >> 3;                    // 0..95
  const int pidx = s / 48;                   // 0..1
  const int sub = s % 48;                    // 0..47
  const int tile = (xcd + 8 * pidx) * 2 + (sub >= 24 ? 1 : 0);
  const int inner = sub % 24;
  const int tn = inner % 6;
  const int sk = inner / 6;                  // split-K 0..3
  int e, tm;
  if (!tile_lookup(counts, tile, e, tm)) return;
  const int Me = counts[e];
  const int prowbase = padded_off(counts, e) + tm * 256;

  __shared__ __align__(16) char Sh[49152];   // [2][A 16K | B 8K]

  const int tid = threadIdx.x;
  const int lane = tid & 63;
  const int w = tid >> 6;
  const int wm = w >> 1, wn = w & 1;

  // ---- A async staging (h rows, bf16), split-K window
  const int c0 = w * 2, c1 = w * 2 + 1;
  const int mA0 = c0 * 16 + (lane >> 2), sA0 = lane & 3;
  const int ko0 = (sA0 - mA0 - (mA0 >> 2)) & 3;
  const char* aSrc0 = (const char*)h + (size_t)(prowbase + mA0) * (HID * 2) + sk * 1024 + ko0 * 16;
  const int mA1 = c1 * 16 + (lane >> 2), sA1 = lane & 3;
  const int ko1 = (sA1 - mA1 - (mA1 >> 2)) & 3;
  const char* aSrc1 = (const char*)h + (size_t)(prowbase + mA1) * (HID * 2) + sk * 1024 + ko1 * 16;

  // ---- B reg-staging: one fp32 column strip per thread
  const int nloc = tid & 127;
  const int koW = tid >> 7;              // 0..3
  const unsigned offBw = (unsigned)(nloc * 4 + ((koW + nloc + (nloc >> 2)) & 3)) * 16;
  const int ncol = tn * 128 + nloc;
  const float* srcD = Wd + (size_t)e * HID * DM + (size_t)(sk * 512 + koW * 8) * DM + ncol;

  const int lc = lane & 15, q = lane >> 4;
  unsigned offA[4], offBr[4];
#pragma unroll
  for (int i = 0; i < 4; ++i) {
    int m = wm * 64 + i * 16 + lc;
    offA[i] = (unsigned)(m * 4 + ((q + m + (m >> 2)) & 3)) * 16;
    int n = wn * 64 + i * 16 + lc;
    offBr[i] = 16384u + (unsigned)(n * 4 + ((q + n + (n >> 2)) & 3)) * 16;
  }

  f32x4 acc[4][4];
#pragma unroll
  for (int i = 0; i < 4; ++i)
#pragma unroll
    for (int j = 0; j < 4; ++j)
#pragma unroll
      for (int k = 0; k < 4; ++k) acc[i][j][k] = 0.f;

  float fd[8];
  // ---- prologue
  ASYNC16(aSrc0, Sh + c0 * 1024); aSrc0 += 64;
  ASYNC16(aSrc1, Sh + c1 * 1024); aSrc1 += 64;
#pragma unroll
  for (int j = 0; j < 8; ++j) fd[j] = srcD[(size_t)j * DM];
  srcD += (size_t)32 * DM;
  {
    uint4 dp;
    dp.x = pack2(fd[0], fd[1]); dp.y = pack2(fd[2], fd[3]);
    dp.z = pack2(fd[4], fd[5]); dp.w = pack2(fd[6], fd[7]);
    *(uint4*)(Sh + 16384 + offBw) = dp;
  }
  __syncthreads();

  for (int kt = 0; kt < 16; ++kt) {
    char* bufc = Sh + (unsigned)(kt & 1) * 24576u;
    char* bufn = Sh + (unsigned)((kt + 1) & 1) * 24576u;
    const bool more = (kt + 1) < 16;
    if (more) {
      ASYNC16(aSrc0, bufn + c0 * 1024); aSrc0 += 64;
      ASYNC16(aSrc1, bufn + c1 * 1024); aSrc1 += 64;
#pragma unroll
      for (int j = 0; j < 8; ++j) fd[j] = srcD[(size_t)j * DM];
      srcD += (size_t)32 * DM;
    }
    bf16x8 a[4], b[4];
#pragma unroll
    for (int i = 0; i < 4; ++i) a[i] = *(const bf16x8*)(bufc + offA[i]);
#pragma unroll
    for (int j = 0; j < 4; ++j) b[j] = *(const bf16x8*)(bufc + offBr[j]);
#pragma unroll
    for (int i = 0; i < 4; ++i)
#pragma unroll
      for (int j = 0; j < 4; ++j)
        acc[i][j] = __builtin_amdgcn_mfma_f32_16x16x32_bf16(a[i], b[j], acc[i][j], 0, 0, 0);
    if (more) {
      uint4 dp;
      dp.x = pack2(fd[0], fd[1]); dp.y = pack2(fd[2], fd[3]);
      dp.z = pack2(fd[4], fd[5]); dp.w = pack2(fd[6], fd[7]);
      *(uint4*)(bufn + 16384 + offBw) = dp;
    }
    __syncthreads();
  }

  const int colbase = tn * 128 + wn * 64;
  const int rlane = (lane >> 4) * 4;
  const int clane = lane & 15;
#pragma unroll
  for (int i = 0; i < 4; ++i) {
#pragma unroll
    for (int rr = 0; rr < 4; ++rr) {
      int rowIn = wm * 64 + i * 16 + rlane + rr;
      if (tm * 256 + rowIn < Me) {
        int tok = tlist[prowbase + rowIn];
        float* yp = y + (size_t)tok * DM + colbase + clane;
#pragma unroll
        for (int j = 0; j < 4; ++j) atomicAdd(&yp[j * 16], acc[i][j][rr]);
      }
    }
  }
}

extern "C" void kernel_launch(void* const* d_in, const int* in_sizes, int n_in,
                              void* d_out, int out_size, void* d_ws, size_t ws_size,
                              hipStream_t stream)
{
  const float* x   = (const float*)d_in[0];
  const float* wgw = (const float*)d_in[1];
  const float* wgb = (const float*)d_in[2];
  const float* Wu  = (const float*)d_in[3];
  const float* Wv  = (const float*)d_in[4];
  const float* Wd  = (const float*)d_in[5];
  float* out = (float*)d_out;

  char* ws = (char*)d_ws;
  int*   counts = (int*)(ws + 0);                         // 8 ints
  int*   eidx   = (int*)(ws + 256);                       // 4096
  float* gatep  = (float*)(ws + 16640);                   // 4096
  int*   prow   = (int*)(ws + 33024);                     // 4096
  float* cepart = (float*)(ws + 49408);                   // 1024*8
  int*   tlist  = (int*)(ws + 82176);                     // 5120 (padded rows)
  float* gate_b = (float*)(ws + 102656);                  // 5120
  unsigned short* xb  = (unsigned short*)(ws + 123136);   // 5120*768 bf16
  unsigned short* h   = (unsigned short*)(ws + 7987456);  // 5120*2048 bf16

  k_gate<<<1024, 256, 0, stream>>>(x, wgw, wgb, eidx, gatep, cepart);
  k_count<<<1, 256, 0, stream>>>(eidx, gatep, cepart, prow, tlist, gate_b,
                                 counts, out + (size_t)TOK * DM);
  k2_scatter_zero<<<1536, 256, 0, stream>>>(x, prow, xb, out);
  k_ffn1<<<512, 512, 0, stream>>>(Wu, Wv, xb, gate_b, counts, h);
  k_ffn2<<<768, 512, 0, stream>>>(Wd, h, counts, tlist, out);
}

// Round 7
// 364.124 us; speedup vs baseline: 1.1533x; 1.0011x over previous
//
#include <hip/hip_runtime.h>
#include <cstdint>
#include <cstddef>

#define TOK 4096
#define DM 768
#define HID 2048
#define NE 8

typedef __attribute__((ext_vector_type(8))) short bf16x8;
typedef __attribute__((ext_vector_type(4))) float f32x4;

// async global->LDS: dest = wave-uniform base + lane*16; SOURCE is per-lane.
#define ASYNC16(GP, LP) \
  __builtin_amdgcn_global_load_lds((__attribute__((address_space(1))) void*)(GP), \
                                   (__attribute__((address_space(3))) void*)(LP), 16, 0, 0)

__device__ __forceinline__ unsigned short f2bf(float f) {
  unsigned int u = __float_as_uint(f);
  u += 0x7FFF + ((u >> 16) & 1);   // RNE
  return (unsigned short)(u >> 16);
}
__device__ __forceinline__ unsigned int pack2(float a, float b) {
  return (unsigned)f2bf(a) | ((unsigned)f2bf(b) << 16);
}
__device__ __forceinline__ int padded_off(const int* counts, int e) {
  int o = 0;
  for (int i = 0; i < e; ++i) o += (counts[i] + 127) & ~127;
  return o;
}

// ---------------- K_gate: gating only (NO atomics) ----------------
__global__ __launch_bounds__(256)
void k_gate(const float* __restrict__ x, const float* __restrict__ wgw,
            const float* __restrict__ wgb,
            int* __restrict__ eidx, float* __restrict__ gatep,
            float* __restrict__ cepart)
{
  __shared__ float ce_loc[4][NE];
  const int lane = threadIdx.x & 63;
  const int w = threadIdx.x >> 6;
  const int t = blockIdx.x * 4 + w;
  float acc[NE];
#pragma unroll
  for (int e = 0; e < NE; ++e) acc[e] = 0.f;
  const float* xr = x + (size_t)t * DM;
#pragma unroll
  for (int j = 0; j < DM / 64; ++j) {
    float xv = xr[j * 64 + lane];
#pragma unroll
    for (int e = 0; e < NE; ++e) acc[e] += xv * wgw[e * DM + j * 64 + lane];
  }
#pragma unroll
  for (int e = 0; e < NE; ++e) {
    float v = acc[e];
#pragma unroll
    for (int off = 32; off >= 1; off >>= 1) v += __shfl_xor(v, off);
    acc[e] = v + wgb[e];
  }
  float mx = acc[0]; int ai = 0;
#pragma unroll
  for (int e = 1; e < NE; ++e) if (acc[e] > mx) { mx = acc[e]; ai = e; }
  float p[NE]; float se = 0.f;
#pragma unroll
  for (int e = 0; e < NE; ++e) { p[e] = expf(acc[e] - mx); se += p[e]; }
  float inv = 1.f / se;
  if (lane == 0) {
#pragma unroll
    for (int e = 0; e < NE; ++e) ce_loc[w][e] = p[e] * inv;
    eidx[t] = ai;
    gatep[t] = p[ai] * inv;
  }
  __syncthreads();
  if (threadIdx.x < NE) {
    float s = ce_loc[0][threadIdx.x] + ce_loc[1][threadIdx.x]
            + ce_loc[2][threadIdx.x] + ce_loc[3][threadIdx.x];
    cepart[blockIdx.x * NE + threadIdx.x] = s;
  }
}

// ---------------- K_convert: fp32 weights -> bf16 blobs ----------------
// Blob: per (expert, 128-col tile): K/32 slabs of 8192 B; slab unit = ko*128+n.
// Wu/Wv path (b < 1536): v2 row-contiguous — each block reads 8 full rows
// (64 KB contiguous), each thread owns an 8x8 (k x n) patch and writes 8
// complete 16-B k-octet units (128 B contiguous). Blob bytes identical to v1.
// Wd path (b >= 1536): original strided-float4 pattern.
__global__ __launch_bounds__(256)
void k_convert(const float* __restrict__ Wu, const float* __restrict__ Wv,
               const float* __restrict__ Wd,
               unsigned short* __restrict__ wub, unsigned short* __restrict__ wvb,
               unsigned short* __restrict__ wdb)
{
  const int b = blockIdx.x;                // 0..3071
  if (b < 1536) {
    // ---- Wu/Wv convert, row-contiguous v2 ----
    const int seg = b / 768;               // 0=Wu 1=Wv
    const int rr = b % 768;
    const int e = rr / 96;
    const int g = rr % 96;                 // 8-row group: k0 = g*8
    const float* W = (seg ? Wv : Wu) + (size_t)e * DM * HID;
    unsigned short* blob = seg ? wvb : wub;
    const int t = threadIdx.x;
    const int nt = t >> 4;                 // n-tile 0..15
    const int ncol = (t & 15) * 8;         // col-in-tile 0..120
    const int k0 = g * 8;
    float4 f[8][2];
    const float4* src = (const float4*)(W + (size_t)k0 * HID) + 2 * t;
#pragma unroll
    for (int j = 0; j < 8; ++j) {
      f[j][0] = src[0]; f[j][1] = src[1];
      src += HID / 4;
    }
    const int kt = k0 >> 5, ko = (k0 >> 3) & 3;
    unsigned short* dst = blob + (((size_t)(e * 16 + nt) * 24 + kt) << 12)
                        + (size_t)(ko * 128 + ncol) * 8;
#pragma unroll
    for (int c = 0; c < 8; ++c) {
      const int h4 = c >> 2, l4 = c & 3;
      uint4 u;
      u.x = pack2(((const float*)&f[0][h4])[l4], ((const float*)&f[1][h4])[l4]);
      u.y = pack2(((const float*)&f[2][h4])[l4], ((const float*)&f[3][h4])[l4]);
      u.z = pack2(((const float*)&f[4][h4])[l4], ((const float*)&f[5][h4])[l4]);
      u.w = pack2(((const float*)&f[6][h4])[l4], ((const float*)&f[7][h4])[l4]);
      *(uint4*)(dst + c * 8) = u;
    }
  } else {
    // ---- Wd convert (original pattern) ----
    const int r = b - 1536;                // 0..1535
    const int e = r / 192;
    const int rem = r % 192;
    const int nt = rem / 32, kt2 = rem % 32;
    const float* W = Wd + (size_t)e * HID * DM;
    unsigned short* blobbase = wdb + ((size_t)((e * 6 + nt) * 64) << 12);
    const int t = threadIdx.x;
    const int n4 = t & 31, ko8 = t >> 5;
    const float* src = W + (size_t)(kt2 * 64 + ko8 * 8) * DM + nt * 128 + n4 * 4;
    float4 f[8];
#pragma unroll
    for (int j = 0; j < 8; ++j) f[j] = *(const float4*)(src + (size_t)j * DM);
    const int kt = kt2 * 2 + (ko8 >> 2), ko = ko8 & 3;
    unsigned short* dst = blobbase + ((size_t)kt << 12) + (size_t)(ko * 128 + n4 * 4) * 8;
#pragma unroll
    for (int i = 0; i < 4; ++i) {
      uint4 u;
      u.x = pack2(((const float*)&f[0])[i], ((const float*)&f[1])[i]);
      u.y = pack2(((const float*)&f[2])[i], ((const float*)&f[3])[i]);
      u.z = pack2(((const float*)&f[4])[i], ((const float*)&f[5])[i]);
      u.w = pack2(((const float*)&f[6])[i], ((const float*)&f[7])[i]);
      *(uint4*)(dst + i * 8) = u;
    }
  }
}

// ---------------- K_count: single-block counting sort + aux ----------------
__global__ __launch_bounds__(256)
void k_count(const int* __restrict__ eidx, const float* __restrict__ gatep,
             const float* __restrict__ cepart,
             int* __restrict__ prow_arr, int* __restrict__ tlist,
             float* __restrict__ gate_b, int* __restrict__ counts_g,
             float* __restrict__ aux_out)
{
  __shared__ int hist[256][NE];
  __shared__ float fs[256][NE];
  __shared__ int po_s[NE], cnt_s[NE];
  const int tid = threadIdx.x;
  int own[NE], v[NE], el[16];
#pragma unroll
  for (int e = 0; e < NE; ++e) own[e] = 0;
#pragma unroll
  for (int j = 0; j < 16; ++j) {
    el[j] = eidx[tid * 16 + j];
#pragma unroll
    for (int e = 0; e < NE; ++e) own[e] += (el[j] == e) ? 1 : 0;
  }
#pragma unroll
  for (int e = 0; e < NE; ++e) { v[e] = own[e]; hist[tid][e] = v[e]; }
  __syncthreads();
  for (int st = 1; st < 256; st <<= 1) {
    int add[NE];
#pragma unroll
    for (int e = 0; e < NE; ++e) add[e] = (tid >= st) ? hist[tid - st][e] : 0;
    __syncthreads();
#pragma unroll
    for (int e = 0; e < NE; ++e) { v[e] += add[e]; hist[tid][e] = v[e]; }
    __syncthreads();
  }
  if (tid == 0) {
    int o = 0;
#pragma unroll
    for (int e = 0; e < NE; ++e) {
      int c = hist[255][e];
      cnt_s[e] = c; counts_g[e] = c; po_s[e] = o;
      o += (c + 127) & ~127;
    }
  }
  __syncthreads();
  int run[NE];
#pragma unroll
  for (int e = 0; e < NE; ++e) run[e] = po_s[e] + v[e] - own[e];
#pragma unroll
  for (int j = 0; j < 16; ++j) {
    const int t = tid * 16 + j;
    const int e = el[j];
    int p = 0;
#pragma unroll
    for (int k = 0; k < NE; ++k) if (e == k) p = run[k]++;
    prow_arr[t] = p;
    tlist[p] = t;
    gate_b[p] = gatep[t];
  }
  // aux reduce
  float s[NE];
#pragma unroll
  for (int e = 0; e < NE; ++e) s[e] = 0.f;
  for (int bb = tid; bb < 1024; bb += 256)
#pragma unroll
    for (int e = 0; e < NE; ++e) s[e] += cepart[bb * NE + e];
#pragma unroll
  for (int e = 0; e < NE; ++e) fs[tid][e] = s[e];
  __syncthreads();
  for (int st = 128; st > 0; st >>= 1) {
    if (tid < st)
#pragma unroll
      for (int e = 0; e < NE; ++e) fs[tid][e] += fs[tid + st][e];
    __syncthreads();
  }
  if (tid == 0) {
    float aux = 0.f;
    for (int e = 0; e < NE; ++e)
      aux += ((float)cnt_s[e] / 4096.f) * (fs[0][e] / 4096.f);
    aux_out[0] = 0.05f * 8.f * aux;
  }
}

// ---------------- K2: scatter x rows (row-major bf16) + zero y ----------------
__global__ __launch_bounds__(256)
void k2_scatter_zero(const float* __restrict__ x, const int* __restrict__ prow_arr,
                     unsigned short* __restrict__ xb, float* __restrict__ y)
{
  const int b = blockIdx.x;
  if (b < 1024) {
    const int lane = threadIdx.x & 63;
    const int w = threadIdx.x >> 6;
    const int t = b * 4 + w;
    const int prow = prow_arr[t];
    const float4* src4 = (const float4*)(x + (size_t)t * DM);
    uint2* dst = (uint2*)(xb + (size_t)prow * DM);
#pragma unroll
    for (int c = 0; c < 3; ++c) {
      float4 v = src4[lane + c * 64];
      uint2 d; d.x = pack2(v.x, v.y); d.y = pack2(v.z, v.w);
      dst[lane + c * 64] = d;
    }
  } else {
    float4* y4 = (float4*)y;
    const int base = (b - 1024) * 1536 + threadIdx.x;
#pragma unroll
    for (int c = 0; c < 6; ++c) {
      float4 z; z.x = 0.f; z.y = 0.f; z.z = 0.f; z.w = 0.f;
      y4[base + c * 256] = z;
    }
  }
}

// ---------------- FFN1: h = silu(x@Wu)*(x@Wv)*gate ----------------
// 128M x 128N, BK=64 (2 sub-iters of 32), waves 2x2. LDS 48 KB dbl-region.
__global__ __launch_bounds__(256, 2)
void k_ffn1(const unsigned short* __restrict__ wub, const unsigned short* __restrict__ wvb,
            const unsigned short* __restrict__ xb, const float* __restrict__ gate_b,
            const int* __restrict__ counts, unsigned short* __restrict__ h)
{
  const int e = blockIdx.z;
  const int Me = counts[e];
  const int tm = blockIdx.y;
  if (tm * 128 >= Me) return;
  const int tn = blockIdx.x;
  const int prowbase = padded_off(counts, e) + tm * 128;

  // regions (8 KB each): [A0][Bu0][Bv0][A1][Bu1][Bv1]
  __shared__ __align__(16) unsigned short Sh[24576];

  const int tid = threadIdx.x;
  const int lane = tid & 63;
  const int wv_ = tid >> 6;
  const int wm = wv_ >> 1, wn = wv_ & 1;
  const int wu_id = __builtin_amdgcn_readfirstlane(wv_);

  f32x4 accU[4][4], accV[4][4];
#pragma unroll
  for (int i = 0; i < 4; ++i)
#pragma unroll
    for (int j = 0; j < 4; ++j)
#pragma unroll
      for (int k = 0; k < 4; ++k) { accU[i][j][k] = 0.f; accV[i][j][k] = 0.f; }

  const char* BuBase = (const char*)wub + ((size_t)((e * 16 + tn) * 24) << 13);
  const char* BvBase = (const char*)wvb + ((size_t)((e * 16 + tn) * 24) << 13);

  const char* sp[12]; size_t stp[12];
#pragma unroll
  for (int c2 = 0; c2 < 12; ++c2) {
    const int c = wu_id * 12 + c2;
    const int reg = c >> 3, i8 = c & 7;
    const int sub = (reg >= 3);
    const int rr = (reg >= 3) ? reg - 3 : reg;
    const int s = i8 * 64 + lane;
    if (rr == 0) {
      int m = s >> 2, ko = (s & 3) ^ (m & 3);
      sp[c2] = (const char*)xb + (size_t)(prowbase + m) * (DM * 2) + sub * 64 + ko * 16;
      stp[c2] = 128;
    } else {
      int n = s >> 2, ko = (s & 3) ^ (n & 3);
      const char* base = (rr == 1) ? BuBase : BvBase;
      sp[c2] = base + (size_t)sub * 8192 + (size_t)(ko * 128 + n) * 16;
      stp[c2] = 16384;
    }
  }
  const int lc = lane & 15, q = lane >> 4;

  for (int kt2 = 0; kt2 < 12; ++kt2) {
#pragma unroll
    for (int c2 = 0; c2 < 12; ++c2) {
      ASYNC16(sp[c2], (char*)Sh + (unsigned)((wu_id * 12 + c2) * 1024));
      sp[c2] += stp[c2];
    }
    __syncthreads();
#pragma unroll
    for (int sub = 0; sub < 2; ++sub) {
      const int sb = sub * 12288;
      bf16x8 a[4], bu[4], bv[4];
#pragma unroll
      for (int i = 0; i < 4; ++i) {
        int m = wm * 64 + i * 16 + lc;
        a[i] = *(const bf16x8*)&Sh[sb + (m * 4 + (q ^ (m & 3))) * 8];
      }
#pragma unroll
      for (int j = 0; j < 4; ++j) {
        int n = wn * 64 + j * 16 + lc;
        int slb = (n * 4 + (q ^ (n & 3))) * 8;
        bu[j] = *(const bf16x8*)&Sh[sb + 4096 + slb];
        bv[j] = *(const bf16x8*)&Sh[sb + 8192 + slb];
      }
#pragma unroll
      for (int i = 0; i < 4; ++i)
#pragma unroll
        for (int j = 0; j < 4; ++j) {
          accU[i][j] = __builtin_amdgcn_mfma_f32_16x16x32_bf16(a[i], bu[j], accU[i][j], 0, 0, 0);
          accV[i][j] = __builtin_amdgcn_mfma_f32_16x16x32_bf16(a[i], bv[j], accV[i][j], 0, 0, 0);
        }
    }
    __syncthreads();
  }
  const int colbase = tn * 128 + wn * 64;
  const int rlane = (lane >> 4) * 4;
  const int clane = lane & 15;
#pragma unroll
  for (int i = 0; i < 4; ++i) {
#pragma unroll
    for (int r = 0; r < 4; ++r) {
      int rowIn = wm * 64 + i * 16 + rlane + r;
      if (tm * 128 + rowIn < Me) {
        int prow = prowbase + rowIn;
        float g = gate_b[prow];
        unsigned short* hp = h + (size_t)prow * HID + colbase + clane;
#pragma unroll
        for (int j = 0; j < 4; ++j) {
          float u_ = accU[i][j][r];
          float v_ = accV[i][j][r];
          float sv = u_ / (1.f + expf(-u_));
          hp[j * 16] = f2bf(sv * v_ * g);
        }
      }
    }
  }
}

// ---------------- FFN2: y += h @ Wd (split-K=4, atomic f32), BK=64 ----------------
__global__ __launch_bounds__(256, 2)
void k_ffn2(const unsigned short* __restrict__ wdb, const unsigned short* __restrict__ h,
            const int* __restrict__ counts, const int* __restrict__ tlist,
            float* __restrict__ y)
{
  const int z = blockIdx.z;
  const int e = z >> 2, split = z & 3;
  const int Me = counts[e];
  const int tm = blockIdx.y;
  if (tm * 128 >= Me) return;
  const int tn = blockIdx.x;
  const int prowbase = padded_off(counts, e) + tm * 128;

  // regions (8 KB each): [A0][B0][A1][B1]
  __shared__ __align__(16) unsigned short Sh[16384];

  const int tid = threadIdx.x;
  const int lane = tid & 63;
  const int wv_ = tid >> 6;
  const int wm = wv_ >> 1, wn = wv_ & 1;
  const int wu_id = __builtin_amdgcn_readfirstlane(wv_);

  f32x4 acc[4][4];
#pragma unroll
  for (int i = 0; i < 4; ++i)
#pragma unroll
    for (int j = 0; j < 4; ++j)
#pragma unroll
      for (int k = 0; k < 4; ++k) acc[i][j][k] = 0.f;

  const char* BdBase = (const char*)wdb + ((size_t)((e * 6 + tn) * 64) << 13);

  const char* sp[8]; size_t stp[8];
#pragma unroll
  for (int c2 = 0; c2 < 8; ++c2) {
    const int c = wu_id * 8 + c2;
    const int reg = c >> 3, i8 = c & 7;         // reg: 0=A0 1=B0 2=A1 3=B1
    const int sub = reg >> 1;
    const int s = i8 * 64 + lane;
    if ((reg & 1) == 0) {
      int m = s >> 2, ko = (s & 3) ^ (m & 3);
      sp[c2] = (const char*)h + (size_t)(prowbase + m) * (HID * 2)
             + split * 1024 + sub * 64 + ko * 16;
      stp[c2] = 128;
    } else {
      int n = s >> 2, ko = (s & 3) ^ (n & 3);
      sp[c2] = BdBase + (size_t)(split * 16 + sub) * 8192 + (size_t)(ko * 128 + n) * 16;
      stp[c2] = 16384;
    }
  }
  const int lc = lane & 15, q = lane >> 4;

  for (int kti = 0; kti < 8; ++kti) {
#pragma unroll
    for (int c2 = 0; c2 < 8; ++c2) {
      ASYNC16(sp[c2], (char*)Sh + (unsigned)((wu_id * 8 + c2) * 1024));
      sp[c2] += stp[c2];
    }
    __syncthreads();
#pragma unroll
    for (int sub = 0; sub < 2; ++sub) {
      const int sb = sub * 8192;
      bf16x8 a[4], bfr[4];
#pragma unroll
      for (int i = 0; i < 4; ++i) {
        int m = wm * 64 + i * 16 + lc;
        a[i] = *(const bf16x8*)&Sh[sb + (m * 4 + (q ^ (m & 3))) * 8];
      }
#pragma unroll
      for (int j = 0; j < 4; ++j) {
        int n = wn * 64 + j * 16 + lc;
        bfr[j] = *(const bf16x8*)&Sh[sb + 4096 + (n * 4 + (q ^ (n & 3))) * 8];
      }
#pragma unroll
      for (int i = 0; i < 4; ++i)
#pragma unroll
        for (int j = 0; j < 4; ++j)
          acc[i][j] = __builtin_amdgcn_mfma_f32_16x16x32_bf16(a[i], bfr[j], acc[i][j], 0, 0, 0);
    }
    __syncthreads();
  }
  const int colbase = tn * 128 + wn * 64;
  const int rlane = (lane >> 4) * 4;
  const int clane = lane & 15;
#pragma unroll
  for (int i = 0; i < 4; ++i) {
#pragma unroll
    for (int r = 0; r < 4; ++r) {
      int rowIn = wm * 64 + i * 16 + rlane + r;
      if (tm * 128 + rowIn < Me) {
        int tok = tlist[prowbase + rowIn];
        float* yp = y + (size_t)tok * DM + colbase + clane;
#pragma unroll
        for (int j = 0; j < 4; ++j) atomicAdd(&yp[j * 16], acc[i][j][r]);
      }
    }
  }
}

extern "C" void kernel_launch(void* const* d_in, const int* in_sizes, int n_in,
                              void* d_out, int out_size, void* d_ws, size_t ws_size,
                              hipStream_t stream)
{
  const float* x   = (const float*)d_in[0];
  const float* wgw = (const float*)d_in[1];
  const float* wgb = (const float*)d_in[2];
  const float* Wu  = (const float*)d_in[3];
  const float* Wv  = (const float*)d_in[4];
  const float* Wd  = (const float*)d_in[5];
  float* out = (float*)d_out;

  char* ws = (char*)d_ws;
  int*   counts = (int*)(ws + 0);                         // 8 ints
  int*   eidx   = (int*)(ws + 256);                       // 4096
  float* gatep  = (float*)(ws + 16640);                   // 4096
  int*   prow   = (int*)(ws + 33024);                     // 4096
  float* cepart = (float*)(ws + 49408);                   // 1024*8
  int*   tlist  = (int*)(ws + 82176);                     // 5120 (padded rows)
  float* gate_b = (float*)(ws + 102656);                  // 5120
  unsigned short* xb  = (unsigned short*)(ws + 123136);   // 5120*768 bf16
  unsigned short* h   = (unsigned short*)(ws + 7987456);  // 5120*2048 bf16
  unsigned short* wub = (unsigned short*)(ws + 28958976); // 25.2 MB
  unsigned short* wvb = (unsigned short*)(ws + 54124800); // 25.2 MB
  unsigned short* wdb = (unsigned short*)(ws + 79290624); // 25.2 MB

  k_gate<<<1024, 256, 0, stream>>>(x, wgw, wgb, eidx, gatep, cepart);
  k_convert<<<3072, 256, 0, stream>>>(Wu, Wv, Wd, wub, wvb, wdb);
  k_count<<<1, 256, 0, stream>>>(eidx, gatep, cepart, prow, tlist, gate_b,
                                 counts, out + (size_t)TOK * DM);
  k2_scatter_zero<<<1536, 256, 0, stream>>>(x, prow, xb, out);
  k_ffn1<<<dim3(16, 32, 8), 256, 0, stream>>>(wub, wvb, xb, gate_b, counts, h);
  k_ffn2<<<dim3(6, 32, 32), 256, 0, stream>>>(wdb, h, counts, tlist, out);
}

// Round 8
// 346.893 us; speedup vs baseline: 1.2106x; 1.0497x over previous
//
#include <hip/hip_runtime.h>
#include <cstdint>
#include <cstddef>

#define TOK 4096
#define DM 768
#define HID 2048
#define NE 8

typedef __attribute__((ext_vector_type(8))) short bf16x8;
typedef __attribute__((ext_vector_type(4))) float f32x4;

// async global->LDS: dest = wave-uniform base + lane*16; SOURCE is per-lane.
#define ASYNC16(GP, LP) \
  __builtin_amdgcn_global_load_lds((__attribute__((address_space(1))) void*)(GP), \
                                   (__attribute__((address_space(3))) void*)(LP), 16, 0, 0)

__device__ __forceinline__ unsigned short f2bf(float f) {
  unsigned int u = __float_as_uint(f);
  u += 0x7FFF + ((u >> 16) & 1);   // RNE
  return (unsigned short)(u >> 16);
}
__device__ __forceinline__ unsigned int pack2(float a, float b) {
  return (unsigned)f2bf(a) | ((unsigned)f2bf(b) << 16);
}
__device__ __forceinline__ int padded_off(const int* counts, int e) {
  int o = 0;
  for (int i = 0; i < e; ++i) o += (counts[i] + 127) & ~127;
  return o;
}

// ---------------- K_pre: gate (blocks 0..1023) + r0 weight convert ----------------
// Gate branch identical to r0 k_gate. Convert branch identical to r0 k_convert
// (cb = b - 1024): per (expert, 128-col tile): K/32 slabs of 8192 B;
// slab unit = ko*128+n. Gate work rides under convert's duration; one launch saved.
__global__ __launch_bounds__(256)
void k_pre(const float* __restrict__ x, const float* __restrict__ wgw,
           const float* __restrict__ wgb,
           const float* __restrict__ Wu, const float* __restrict__ Wv,
           const float* __restrict__ Wd,
           int* __restrict__ eidx, float* __restrict__ gatep,
           float* __restrict__ cepart,
           unsigned short* __restrict__ wub, unsigned short* __restrict__ wvb,
           unsigned short* __restrict__ wdb)
{
  __shared__ float ce_loc[4][NE];
  const int b = blockIdx.x;
  if (b < 1024) {
    // ---- gating (r0 k_gate) ----
    const int lane = threadIdx.x & 63;
    const int w = threadIdx.x >> 6;
    const int t = b * 4 + w;
    float acc[NE];
#pragma unroll
    for (int e = 0; e < NE; ++e) acc[e] = 0.f;
    const float* xr = x + (size_t)t * DM;
#pragma unroll
    for (int j = 0; j < DM / 64; ++j) {
      float xv = xr[j * 64 + lane];
#pragma unroll
      for (int e = 0; e < NE; ++e) acc[e] += xv * wgw[e * DM + j * 64 + lane];
    }
#pragma unroll
    for (int e = 0; e < NE; ++e) {
      float v = acc[e];
#pragma unroll
      for (int off = 32; off >= 1; off >>= 1) v += __shfl_xor(v, off);
      acc[e] = v + wgb[e];
    }
    float mx = acc[0]; int ai = 0;
#pragma unroll
    for (int e = 1; e < NE; ++e) if (acc[e] > mx) { mx = acc[e]; ai = e; }
    float p[NE]; float se = 0.f;
#pragma unroll
    for (int e = 0; e < NE; ++e) { p[e] = expf(acc[e] - mx); se += p[e]; }
    float inv = 1.f / se;
    if (lane == 0) {
#pragma unroll
      for (int e = 0; e < NE; ++e) ce_loc[w][e] = p[e] * inv;
      eidx[t] = ai;
      gatep[t] = p[ai] * inv;
    }
    __syncthreads();
    if (threadIdx.x < NE) {
      float s = ce_loc[0][threadIdx.x] + ce_loc[1][threadIdx.x]
              + ce_loc[2][threadIdx.x] + ce_loc[3][threadIdx.x];
      cepart[b * NE + threadIdx.x] = s;
    }
  } else {
    // ---- weight convert (r0 k_convert, cb = b - 1024, 0..4607) ----
    const int cb = b - 1024;
    const int seg = cb / 1536;               // 0=Wu 1=Wv 2=Wd
    const int r = cb % 1536;
    const int e = r / 192;
    const int rem = r % 192;
    const float* W;
    unsigned short* blobbase;
    int N, nt, kt2;
    if (seg < 2) {
      N = HID; nt = rem / 12; kt2 = rem % 12;            // K=768: 12 x 64k
      W = ((seg == 0) ? Wu : Wv) + (size_t)e * DM * HID;
      blobbase = ((seg == 0) ? wub : wvb) + ((size_t)((e * 16 + nt) * 24) << 12);
    } else {
      N = DM; nt = rem / 32; kt2 = rem % 32;             // K=2048: 32 x 64k
      W = Wd + (size_t)e * HID * DM;
      blobbase = wdb + ((size_t)((e * 6 + nt) * 64) << 12);
    }
    const int t = threadIdx.x;
    const int n4 = t & 31, ko8 = t >> 5;                 // 32 n-quads x 8 k-octets
    const float* src = W + (size_t)(kt2 * 64 + ko8 * 8) * N + nt * 128 + n4 * 4;
    float4 f[8];
#pragma unroll
    for (int j = 0; j < 8; ++j) f[j] = *(const float4*)(src + (size_t)j * N);
    const int kt = kt2 * 2 + (ko8 >> 2), ko = ko8 & 3;
    unsigned short* dst = blobbase + ((size_t)kt << 12) + (size_t)(ko * 128 + n4 * 4) * 8;
#pragma unroll
    for (int i = 0; i < 4; ++i) {
      uint4 u;
      u.x = pack2(((const float*)&f[0])[i], ((const float*)&f[1])[i]);
      u.y = pack2(((const float*)&f[2])[i], ((const float*)&f[3])[i]);
      u.z = pack2(((const float*)&f[4])[i], ((const float*)&f[5])[i]);
      u.w = pack2(((const float*)&f[6])[i], ((const float*)&f[7])[i]);
      *(uint4*)(dst + i * 8) = u;
    }
  }
}

// ---------------- K_count: single-block counting sort + aux ----------------
__global__ __launch_bounds__(256)
void k_count(const int* __restrict__ eidx, const float* __restrict__ gatep,
             const float* __restrict__ cepart,
             int* __restrict__ prow_arr, int* __restrict__ tlist,
             float* __restrict__ gate_b, int* __restrict__ counts_g,
             float* __restrict__ aux_out)
{
  __shared__ int hist[256][NE];
  __shared__ float fs[256][NE];
  __shared__ int po_s[NE], cnt_s[NE];
  const int tid = threadIdx.x;
  int own[NE], v[NE], el[16];
#pragma unroll
  for (int e = 0; e < NE; ++e) own[e] = 0;
#pragma unroll
  for (int j = 0; j < 16; ++j) {
    el[j] = eidx[tid * 16 + j];
#pragma unroll
    for (int e = 0; e < NE; ++e) own[e] += (el[j] == e) ? 1 : 0;
  }
#pragma unroll
  for (int e = 0; e < NE; ++e) { v[e] = own[e]; hist[tid][e] = v[e]; }
  __syncthreads();
  for (int st = 1; st < 256; st <<= 1) {
    int add[NE];
#pragma unroll
    for (int e = 0; e < NE; ++e) add[e] = (tid >= st) ? hist[tid - st][e] : 0;
    __syncthreads();
#pragma unroll
    for (int e = 0; e < NE; ++e) { v[e] += add[e]; hist[tid][e] = v[e]; }
    __syncthreads();
  }
  if (tid == 0) {
    int o = 0;
#pragma unroll
    for (int e = 0; e < NE; ++e) {
      int c = hist[255][e];
      cnt_s[e] = c; counts_g[e] = c; po_s[e] = o;
      o += (c + 127) & ~127;
    }
  }
  __syncthreads();
  int run[NE];
#pragma unroll
  for (int e = 0; e < NE; ++e) run[e] = po_s[e] + v[e] - own[e];
#pragma unroll
  for (int j = 0; j < 16; ++j) {
    const int t = tid * 16 + j;
    const int e = el[j];
    int p = 0;
#pragma unroll
    for (int k = 0; k < NE; ++k) if (e == k) p = run[k]++;
    prow_arr[t] = p;
    tlist[p] = t;
    gate_b[p] = gatep[t];
  }
  // aux reduce
  float s[NE];
#pragma unroll
  for (int e = 0; e < NE; ++e) s[e] = 0.f;
  for (int bb = tid; bb < 1024; bb += 256)
#pragma unroll
    for (int e = 0; e < NE; ++e) s[e] += cepart[bb * NE + e];
#pragma unroll
  for (int e = 0; e < NE; ++e) fs[tid][e] = s[e];
  __syncthreads();
  for (int st = 128; st > 0; st >>= 1) {
    if (tid < st)
#pragma unroll
      for (int e = 0; e < NE; ++e) fs[tid][e] += fs[tid + st][e];
    __syncthreads();
  }
  if (tid == 0) {
    float aux = 0.f;
    for (int e = 0; e < NE; ++e)
      aux += ((float)cnt_s[e] / 4096.f) * (fs[0][e] / 4096.f);
    aux_out[0] = 0.05f * 8.f * aux;
  }
}

// ---------------- K2: scatter x rows (row-major bf16) ----------------
// y-zeroing removed: ffn2 (split-K=1) writes every y element exactly once.
__global__ __launch_bounds__(256)
void k2_scatter(const float* __restrict__ x, const int* __restrict__ prow_arr,
                unsigned short* __restrict__ xb)
{
  const int b = blockIdx.x;
  const int lane = threadIdx.x & 63;
  const int w = threadIdx.x >> 6;
  const int t = b * 4 + w;
  const int prow = prow_arr[t];
  const float4* src4 = (const float4*)(x + (size_t)t * DM);
  uint2* dst = (uint2*)(xb + (size_t)prow * DM);
#pragma unroll
  for (int c = 0; c < 3; ++c) {
    float4 v = src4[lane + c * 64];
    uint2 d; d.x = pack2(v.x, v.y); d.y = pack2(v.z, v.w);
    dst[lane + c * 64] = d;
  }
}

// ---------------- FFN1: h = silu(x@Wu)*(x@Wv)*gate ----------------
// 128M x 128N, BK=64 (2 sub-iters of 32), waves 2x2. LDS 48 KB dbl-region.
// Proven 71-us configuration (2 blocks/CU, all-ASYNC16 staging). Unchanged.
__global__ __launch_bounds__(256, 2)
void k_ffn1(const unsigned short* __restrict__ wub, const unsigned short* __restrict__ wvb,
            const unsigned short* __restrict__ xb, const float* __restrict__ gate_b,
            const int* __restrict__ counts, unsigned short* __restrict__ h)
{
  const int e = blockIdx.z;
  const int Me = counts[e];
  const int tm = blockIdx.y;
  if (tm * 128 >= Me) return;
  const int tn = blockIdx.x;
  const int prowbase = padded_off(counts, e) + tm * 128;

  // regions (8 KB each): [A0][Bu0][Bv0][A1][Bu1][Bv1]
  __shared__ __align__(16) unsigned short Sh[24576];

  const int tid = threadIdx.x;
  const int lane = tid & 63;
  const int wv_ = tid >> 6;
  const int wm = wv_ >> 1, wn = wv_ & 1;
  const int wu_id = __builtin_amdgcn_readfirstlane(wv_);

  f32x4 accU[4][4], accV[4][4];
#pragma unroll
  for (int i = 0; i < 4; ++i)
#pragma unroll
    for (int j = 0; j < 4; ++j)
#pragma unroll
      for (int k = 0; k < 4; ++k) { accU[i][j][k] = 0.f; accV[i][j][k] = 0.f; }

  const char* BuBase = (const char*)wub + ((size_t)((e * 16 + tn) * 24) << 13);
  const char* BvBase = (const char*)wvb + ((size_t)((e * 16 + tn) * 24) << 13);

  const char* sp[12]; size_t stp[12];
#pragma unroll
  for (int c2 = 0; c2 < 12; ++c2) {
    const int c = wu_id * 12 + c2;
    const int reg = c >> 3, i8 = c & 7;
    const int sub = (reg >= 3);
    const int rr = (reg >= 3) ? reg - 3 : reg;
    const int s = i8 * 64 + lane;
    if (rr == 0) {
      int m = s >> 2, ko = (s & 3) ^ (m & 3);
      sp[c2] = (const char*)xb + (size_t)(prowbase + m) * (DM * 2) + sub * 64 + ko * 16;
      stp[c2] = 128;
    } else {
      int n = s >> 2, ko = (s & 3) ^ (n & 3);
      const char* base = (rr == 1) ? BuBase : BvBase;
      sp[c2] = base + (size_t)sub * 8192 + (size_t)(ko * 128 + n) * 16;
      stp[c2] = 16384;
    }
  }
  const int lc = lane & 15, q = lane >> 4;

  for (int kt2 = 0; kt2 < 12; ++kt2) {
#pragma unroll
    for (int c2 = 0; c2 < 12; ++c2) {
      ASYNC16(sp[c2], (char*)Sh + (unsigned)((wu_id * 12 + c2) * 1024));
      sp[c2] += stp[c2];
    }
    __syncthreads();
#pragma unroll
    for (int sub = 0; sub < 2; ++sub) {
      const int sb = sub * 12288;
      bf16x8 a[4], bu[4], bv[4];
#pragma unroll
      for (int i = 0; i < 4; ++i) {
        int m = wm * 64 + i * 16 + lc;
        a[i] = *(const bf16x8*)&Sh[sb + (m * 4 + (q ^ (m & 3))) * 8];
      }
#pragma unroll
      for (int j = 0; j < 4; ++j) {
        int n = wn * 64 + j * 16 + lc;
        int slb = (n * 4 + (q ^ (n & 3))) * 8;
        bu[j] = *(const bf16x8*)&Sh[sb + 4096 + slb];
        bv[j] = *(const bf16x8*)&Sh[sb + 8192 + slb];
      }
#pragma unroll
      for (int i = 0; i < 4; ++i)
#pragma unroll
        for (int j = 0; j < 4; ++j) {
          accU[i][j] = __builtin_amdgcn_mfma_f32_16x16x32_bf16(a[i], bu[j], accU[i][j], 0, 0, 0);
          accV[i][j] = __builtin_amdgcn_mfma_f32_16x16x32_bf16(a[i], bv[j], accV[i][j], 0, 0, 0);
        }
    }
    __syncthreads();
  }
  const int colbase = tn * 128 + wn * 64;
  const int rlane = (lane >> 4) * 4;
  const int clane = lane & 15;
#pragma unroll
  for (int i = 0; i < 4; ++i) {
#pragma unroll
    for (int r = 0; r < 4; ++r) {
      int rowIn = wm * 64 + i * 16 + rlane + r;
      if (tm * 128 + rowIn < Me) {
        int prow = prowbase + rowIn;
        float g = gate_b[prow];
        unsigned short* hp = h + (size_t)prow * HID + colbase + clane;
#pragma unroll
        for (int j = 0; j < 4; ++j) {
          float u_ = accU[i][j][r];
          float v_ = accV[i][j][r];
          float sv = u_ / (1.f + expf(-u_));
          hp[j * 16] = f2bf(sv * v_ * g);
        }
      }
    }
  }
}

// ---------------- FFN2: y = h @ Wd (split-K=1, plain stores), BK=64 ----------------
// Full K=2048 per block (32 kti iters); each y element has exactly one writer
// -> no atomics, no y-zero prepass. Staging structure identical to r0.
__global__ __launch_bounds__(256, 2)
void k_ffn2(const unsigned short* __restrict__ wdb, const unsigned short* __restrict__ h,
            const int* __restrict__ counts, const int* __restrict__ tlist,
            float* __restrict__ y)
{
  const int e = blockIdx.z;
  const int Me = counts[e];
  const int tm = blockIdx.y;
  if (tm * 128 >= Me) return;
  const int tn = blockIdx.x;
  const int prowbase = padded_off(counts, e) + tm * 128;

  // regions (8 KB each): [A0][B0][A1][B1]
  __shared__ __align__(16) unsigned short Sh[16384];

  const int tid = threadIdx.x;
  const int lane = tid & 63;
  const int wv_ = tid >> 6;
  const int wm = wv_ >> 1, wn = wv_ & 1;
  const int wu_id = __builtin_amdgcn_readfirstlane(wv_);

  f32x4 acc[4][4];
#pragma unroll
  for (int i = 0; i < 4; ++i)
#pragma unroll
    for (int j = 0; j < 4; ++j)
#pragma unroll
      for (int k = 0; k < 4; ++k) acc[i][j][k] = 0.f;

  const char* BdBase = (const char*)wdb + ((size_t)((e * 6 + tn) * 64) << 13);

  const char* sp[8]; size_t stp[8];
#pragma unroll
  for (int c2 = 0; c2 < 8; ++c2) {
    const int c = wu_id * 8 + c2;
    const int reg = c >> 3, i8 = c & 7;         // reg: 0=A0 1=B0 2=A1 3=B1
    const int sub = reg >> 1;
    const int s = i8 * 64 + lane;
    if ((reg & 1) == 0) {
      int m = s >> 2, ko = (s & 3) ^ (m & 3);
      sp[c2] = (const char*)h + (size_t)(prowbase + m) * (HID * 2)
             + sub * 64 + ko * 16;
      stp[c2] = 128;
    } else {
      int n = s >> 2, ko = (s & 3) ^ (n & 3);
      sp[c2] = BdBase + (size_t)sub * 8192 + (size_t)(ko * 128 + n) * 16;
      stp[c2] = 16384;
    }
  }
  const int lc = lane & 15, q = lane >> 4;

  for (int kti = 0; kti < 32; ++kti) {
#pragma unroll
    for (int c2 = 0; c2 < 8; ++c2) {
      ASYNC16(sp[c2], (char*)Sh + (unsigned)((wu_id * 8 + c2) * 1024));
      sp[c2] += stp[c2];
    }
    __syncthreads();
#pragma unroll
    for (int sub = 0; sub < 2; ++sub) {
      const int sb = sub * 8192;
      bf16x8 a[4], bfr[4];
#pragma unroll
      for (int i = 0; i < 4; ++i) {
        int m = wm * 64 + i * 16 + lc;
        a[i] = *(const bf16x8*)&Sh[sb + (m * 4 + (q ^ (m & 3))) * 8];
      }
#pragma unroll
      for (int j = 0; j < 4; ++j) {
        int n = wn * 64 + j * 16 + lc;
        bfr[j] = *(const bf16x8*)&Sh[sb + 4096 + (n * 4 + (q ^ (n & 3))) * 8];
      }
#pragma unroll
      for (int i = 0; i < 4; ++i)
#pragma unroll
        for (int j = 0; j < 4; ++j)
          acc[i][j] = __builtin_amdgcn_mfma_f32_16x16x32_bf16(a[i], bfr[j], acc[i][j], 0, 0, 0);
    }
    __syncthreads();
  }
  const int colbase = tn * 128 + wn * 64;
  const int rlane = (lane >> 4) * 4;
  const int clane = lane & 15;
#pragma unroll
  for (int i = 0; i < 4; ++i) {
#pragma unroll
    for (int r = 0; r < 4; ++r) {
      int rowIn = wm * 64 + i * 16 + rlane + r;
      if (tm * 128 + rowIn < Me) {
        int tok = tlist[prowbase + rowIn];
        float* yp = y + (size_t)tok * DM + colbase + clane;
#pragma unroll
        for (int j = 0; j < 4; ++j) yp[j * 16] = acc[i][j][r];
      }
    }
  }
}

extern "C" void kernel_launch(void* const* d_in, const int* in_sizes, int n_in,
                              void* d_out, int out_size, void* d_ws, size_t ws_size,
                              hipStream_t stream)
{
  const float* x   = (const float*)d_in[0];
  const float* wgw = (const float*)d_in[1];
  const float* wgb = (const float*)d_in[2];
  const float* Wu  = (const float*)d_in[3];
  const float* Wv  = (const float*)d_in[4];
  const float* Wd  = (const float*)d_in[5];
  float* out = (float*)d_out;

  char* ws = (char*)d_ws;
  int*   counts = (int*)(ws + 0);                         // 8 ints
  int*   eidx   = (int*)(ws + 256);                       // 4096
  float* gatep  = (float*)(ws + 16640);                   // 4096
  int*   prow   = (int*)(ws + 33024);                     // 4096
  float* cepart = (float*)(ws + 49408);                   // 1024*8
  int*   tlist  = (int*)(ws + 82176);                     // 5120 (padded rows)
  float* gate_b = (float*)(ws + 102656);                  // 5120
  unsigned short* xb  = (unsigned short*)(ws + 123136);   // 5120*768 bf16
  unsigned short* h   = (unsigned short*)(ws + 7987456);  // 5120*2048 bf16
  unsigned short* wub = (unsigned short*)(ws + 28958976); // 25.2 MB
  unsigned short* wvb = (unsigned short*)(ws + 54124800); // 25.2 MB
  unsigned short* wdb = (unsigned short*)(ws + 79290624); // 25.2 MB

  k_pre<<<1024 + 4608, 256, 0, stream>>>(x, wgw, wgb, Wu, Wv, Wd,
                                         eidx, gatep, cepart, wub, wvb, wdb);
  k_count<<<1, 256, 0, stream>>>(eidx, gatep, cepart, prow, tlist, gate_b,
                                 counts, out + (size_t)TOK * DM);
  k2_scatter<<<1024, 256, 0, stream>>>(x, prow, xb);
  k_ffn1<<<dim3(16, 32, 8), 256, 0, stream>>>(wub, wvb, xb, gate_b, counts, h);
  k_ffn2<<<dim3(6, 32, 8), 256, 0, stream>>>(wdb, h, counts, tlist, out);
}